// Round 8
// baseline (542.808 us; speedup 1.0000x reference)
//
#include <hip/hip_runtime.h>
#include <hip/hip_bf16.h>

#define T_TOK 4096
#define H_DIM 1024
#define E_EXP 32
#define TOPK 4
#define CAP 1024
#define PAIRS (T_TOK*TOPK)

typedef __attribute__((ext_vector_type(8))) short short8v;
typedef __attribute__((ext_vector_type(4))) float f32x4;
typedef unsigned long long u64;
typedef unsigned short ushort;

__device__ __forceinline__ float bf16_bits_to_f32(ushort h) {
    return __uint_as_float(((unsigned)h) << 16);
}
__device__ __forceinline__ unsigned bf16r(float f) {
    unsigned u = __float_as_uint(f);
    return ((u + 0x7fffu + ((u >> 16) & 1u)) >> 16) & 0xffffu;
}
// v_cvt_pk_bf16_f32: D[15:0]=bf16(a), D[31:16]=bf16(b)
__device__ __forceinline__ unsigned cvt2(float a, float b) {
    unsigned r;
    asm("v_cvt_pk_bf16_f32 %0, %1, %2" : "=v"(r) : "v"(a), "v"(b));
    return r;
}

#define GLD16(gsrc, ldst) \
    __builtin_amdgcn_global_load_lds( \
        (const __attribute__((address_space(1))) unsigned*)(gsrc), \
        (__attribute__((address_space(3))) unsigned*)(ldst), 16, 0, 0)

// ---------------- router ----------------
__global__ __launch_bounds__(256) void router_kernel(
    const float* __restrict__ x, const float* __restrict__ rw,
    const float* __restrict__ rb, float* __restrict__ scores,
    int* __restrict__ flat_e, float* __restrict__ flat_w)
{
    __shared__ float xs[H_DIM];
    __shared__ float lg[E_EXP];
    __shared__ float sw[TOPK];
    __shared__ int   se[TOPK];
    const int t = blockIdx.x;
    const int tid = threadIdx.x;

    for (int i = tid; i < H_DIM; i += 256) xs[i] = x[(size_t)t * H_DIM + i];
    __syncthreads();

    const int e = tid >> 3, l8 = tid & 7;
    float partial = 0.f;
    const float* wr = rw + (size_t)e * H_DIM;
    for (int h = l8; h < H_DIM; h += 8) partial += xs[h] * wr[h];
    partial += __shfl_xor(partial, 1);
    partial += __shfl_xor(partial, 2);
    partial += __shfl_xor(partial, 4);
    if (l8 == 0) lg[e] = partial + rb[e];
    __syncthreads();

    if (tid == 0) {
        unsigned used = 0;
        float bv[TOPK]; int bi[TOPK];
        #pragma unroll
        for (int j = 0; j < TOPK; j++) {
            float best = -1e30f; int bid = -1;
            for (int q = 0; q < E_EXP; q++) {
                if (used & (1u << q)) continue;
                if (lg[q] > best) { best = lg[q]; bid = q; }
            }
            used |= 1u << bid;
            bv[j] = best; bi[j] = bid;
        }
        const float m = bv[0];
        float s = 0.f; float w[TOPK];
        #pragma unroll
        for (int j = 0; j < TOPK; j++) { w[j] = expf(bv[j] - m); s += w[j]; }
        const float inv = 1.f / s;
        #pragma unroll
        for (int j = 0; j < TOPK; j++) { sw[j] = w[j] * inv; se[j] = bi[j]; }
    }
    __syncthreads();

    if (tid < E_EXP) {
        float v = 0.f;
        #pragma unroll
        for (int j = 0; j < TOPK; j++) if (se[j] == tid) v = sw[j];
        scores[(size_t)t * E_EXP + tid] = v;
    }
    if (tid < TOPK) {
        flat_e[t * TOPK + tid] = se[tid];
        flat_w[t * TOPK + tid] = sw[tid];
    }
}

// ---------------- deterministic rank scan + tile list + ticket reset ----------------
__global__ __launch_bounds__(256) void scan_kernel(
    const int* __restrict__ flat_e, const float* __restrict__ flat_w,
    int* __restrict__ slot_token, float* __restrict__ slot_w,
    int* __restrict__ pair_slot, int* __restrict__ counts,
    int* __restrict__ tile_list, int* __restrict__ meta)
{
    __shared__ int cnt[256 * E_EXP];
    const int tid = threadIdx.x;
    for (int e = 0; e < E_EXP; e++) cnt[tid * E_EXP + e] = 0;
    __syncthreads();
    const int base = tid * (PAIRS / 256);
    for (int i = 0; i < PAIRS / 256; i++) {
        int e = flat_e[base + i];
        cnt[tid * E_EXP + e]++;
    }
    __syncthreads();
    if (tid < E_EXP) {
        int run = 0;
        for (int i = 0; i < 256; i++) {
            int idx = i * E_EXP + tid;
            int v = cnt[idx];
            cnt[idx] = run;
            run += v;
        }
        counts[tid] = min(run, CAP);
    }
    __syncthreads();
    if (tid == 0) {
        int idx = 0;
        for (int e = 0; e < E_EXP; e++) {
            int nt = (counts[e] + 127) >> 7;
            for (int rt = 0; rt < nt; rt++) tile_list[idx++] = (e << 3) | rt;
        }
        meta[0] = idx;   // n_tiles
        meta[1] = 0;     // gateup ticket
        meta[2] = 0;     // down ticket
    }
    __syncthreads();
    for (int i = 0; i < PAIRS / 256; i++) {
        int p = base + i;
        int e = flat_e[p];
        int r = cnt[tid * E_EXP + e]++;
        if (r < CAP) {
            slot_token[e * CAP + r] = p >> 2;
            slot_w[e * CAP + r] = flat_w[p];
            pair_slot[p] = r;
        } else {
            pair_slot[p] = -1;
        }
    }
}

// ---------------- stage tokens: gather x -> granule-packed bf16 xbuf ----------------
__global__ __launch_bounds__(256) void stage_tokens(
    const float* __restrict__ x, const int* __restrict__ slot_token,
    const int* __restrict__ counts, char* __restrict__ xbuf)
{
    const int e = blockIdx.y, rt = blockIdx.x;
    const int n = counts[e];
    const int row0 = rt * 128;
    if (row0 >= n) return;
    const int rows_here = min(128, n - row0);
    const int lane = threadIdx.x & 63, wv = threadIdx.x >> 6;
    char* tb = xbuf + ((size_t)(e * 8 + rt)) * 262144;

    for (int r = wv; r < rows_here; r += 4) {
        const float* xr = x + (size_t)slot_token[e * CAP + row0 + r] * H_DIM;
        const int s = (r >> 1) & 3;
        #pragma unroll
        for (int half = 0; half < 2; ++half) {
            int gi = half * 64 + lane;
            float4 a = *(const float4*)(xr + gi * 8);
            float4 b = *(const float4*)(xr + gi * 8 + 4);
            uint4 w;
            w.x = cvt2(a.x, a.y); w.y = cvt2(a.z, a.w);
            w.z = cvt2(b.x, b.y); w.w = cvt2(b.z, b.w);
            int t = gi >> 2, kq = gi & 3;
            *(uint4*)(tb + (size_t)t * 8192 + r * 64 + ((kq ^ s) * 16)) = w;
        }
    }
}

// ---------------- convert gate_up weights -> packed bf16 (256 gu-col panels) ----------------
__global__ __launch_bounds__(256) void conv_gu(
    const float* __restrict__ wgu, char* __restrict__ wbuf)
{
    const int ct = blockIdx.x;      // 0..7
    const int tseg = blockIdx.y;    // 0..3
    const int e = blockIdx.z;       // 0..31
    const int f = threadIdx.x & 127;
    const int h = threadIdx.x >> 7;
    char* dst_base = wbuf + ((size_t)(e * 8 + ct)) * 524288;
    #pragma unroll
    for (int i = 0; i < 4; ++i) {
        const int t = tseg * 8 + h * 4 + i;
        const float* src = wgu + ((size_t)e * 1024 + t * 32) * 2048 + ct * 256 + 2 * f;
        float2 v[32];
        #pragma unroll
        for (int k = 0; k < 32; ++k) v[k] = *(const float2*)(src + (size_t)k * 2048);
        char* dst = dst_base + (size_t)t * 16384 + f * 16;
        #pragma unroll
        for (int kq = 0; kq < 4; ++kq) {
            uint4 g, u;
            g.x = cvt2(v[kq*8+0].x, v[kq*8+1].x); g.y = cvt2(v[kq*8+2].x, v[kq*8+3].x);
            g.z = cvt2(v[kq*8+4].x, v[kq*8+5].x); g.w = cvt2(v[kq*8+6].x, v[kq*8+7].x);
            u.x = cvt2(v[kq*8+0].y, v[kq*8+1].y); u.y = cvt2(v[kq*8+2].y, v[kq*8+3].y);
            u.z = cvt2(v[kq*8+4].y, v[kq*8+5].y); u.w = cvt2(v[kq*8+6].y, v[kq*8+7].y);
            *(uint4*)(dst + kq * 2048) = g;
            *(uint4*)(dst + 8192 + kq * 2048) = u;
        }
    }
}

// ---------------- convert down weights -> packed bf16 ----------------
__global__ __launch_bounds__(256) void conv_dn(
    const float* __restrict__ wd, char* __restrict__ wbuf)
{
    const int ct = blockIdx.x;   // 0..7
    const int tseg = blockIdx.y; // 0..7
    const int e = blockIdx.z;    // 0..31
    const int lane = threadIdx.x & 63, wv = threadIdx.x >> 6;
    const int t = tseg * 4 + wv;
    const float* src = wd + ((size_t)e * 1024 + t * 32) * 1024 + ct * 128 + 2 * lane;
    float2 v[32];
    #pragma unroll
    for (int k = 0; k < 32; ++k) v[k] = *(const float2*)(src + (size_t)k * 1024);
    char* dst = wbuf + (((size_t)(e * 8 + ct) * 32) + t) * 8192 + (2 * lane) * 16;
    #pragma unroll
    for (int kq = 0; kq < 4; ++kq) {
        uint4 g0, g1;
        g0.x = cvt2(v[kq*8+0].x, v[kq*8+1].x); g0.y = cvt2(v[kq*8+2].x, v[kq*8+3].x);
        g0.z = cvt2(v[kq*8+4].x, v[kq*8+5].x); g0.w = cvt2(v[kq*8+6].x, v[kq*8+7].x);
        g1.x = cvt2(v[kq*8+0].y, v[kq*8+1].y); g1.y = cvt2(v[kq*8+2].y, v[kq*8+3].y);
        g1.z = cvt2(v[kq*8+4].y, v[kq*8+5].y); g1.w = cvt2(v[kq*8+6].y, v[kq*8+7].y);
        *(uint4*)(dst + kq * 2048) = g0;
        *(uint4*)(dst + kq * 2048 + 16) = g1;
    }
}

// ---------------- gate_up MFMA GEMM: persistent work-stealing ----------------
__global__ __launch_bounds__(256, 2) void gateup_mfma(
    const char* __restrict__ xbuf, const char* __restrict__ wbuf,
    const float* __restrict__ gub, const int* __restrict__ counts,
    const int* __restrict__ tile_list, int* __restrict__ meta,
    char* __restrict__ act)
{
    __shared__ char AsB[2][8192];
    __shared__ char BsB[2][16384];
    __shared__ int s_tk;

    const int tid = threadIdx.x;
    const int lane = tid & 63, wid = tid >> 6;
    const int wr = wid >> 1, wc = wid & 1;
    const int l15 = lane & 15, l4 = lane >> 4;
    const int nw = meta[0] * 8;

    for (;;) {
        if (tid == 0) s_tk = atomicAdd(&meta[1], 1);
        __syncthreads();
        const int tk = s_tk;
        if (tk >= nw) break;
        const int pr = tile_list[tk >> 3];
        const int e = pr >> 3, rt = pr & 7, ct = tk & 7;

        const int n = counts[e];
        const int row0 = rt * 128;
        const int rows_here = min(128, n - row0);

        const char* xtile = xbuf + ((size_t)(e * 8 + rt)) * 262144;
        const char* btile = wbuf + ((size_t)(e * 8 + ct)) * 524288;

        f32x4 accg[4][4], accu[4][4];
        #pragma unroll
        for (int m = 0; m < 4; m++)
            #pragma unroll
            for (int j = 0; j < 4; j++) { accg[m][j] = (f32x4)0.f; accu[m][j] = (f32x4)0.f; }

        auto stage = [&](int buf, int t) {
            const char* sa = xtile + (size_t)t * 8192 + tid * 16;
            GLD16(sa, AsB[buf] + tid * 16);
            GLD16(sa + 4096, AsB[buf] + 4096 + tid * 16);
            const char* sb = btile + (size_t)t * 16384 + tid * 16;
            GLD16(sb, BsB[buf] + tid * 16);
            GLD16(sb + 4096,  BsB[buf] + 4096  + tid * 16);
            GLD16(sb + 8192,  BsB[buf] + 8192  + tid * 16);
            GLD16(sb + 12288, BsB[buf] + 12288 + tid * 16);
        };

        stage(0, 0);
        __syncthreads();
        int cur = 0;
        for (int t = 0; t < 32; ++t) {
            if (t < 31) stage(cur ^ 1, t + 1);

            short8v afr[4];
            #pragma unroll
            for (int m = 0; m < 4; ++m) {
                int row = wr * 64 + m * 16 + l15;
                afr[m] = *(short8v*)(AsB[cur] + row * 64 + ((l4 ^ ((row >> 1) & 3)) * 16));
            }
            __builtin_amdgcn_s_setprio(1);
            #pragma unroll
            for (int j = 0; j < 4; ++j) {
                int fl = wc * 64 + j * 16 + l15;
                short8v bg8 = *(short8v*)(BsB[cur] + l4 * 2048 + fl * 16);
                short8v bu8 = *(short8v*)(BsB[cur] + 8192 + l4 * 2048 + fl * 16);
                #pragma unroll
                for (int m = 0; m < 4; ++m) {
                    accg[m][j] = __builtin_amdgcn_mfma_f32_16x16x32_bf16(afr[m], bg8, accg[m][j], 0, 0, 0);
                    accu[m][j] = __builtin_amdgcn_mfma_f32_16x16x32_bf16(afr[m], bu8, accu[m][j], 0, 0, 0);
                }
            }
            __builtin_amdgcn_s_setprio(0);
            __syncthreads();
            cur ^= 1;
        }

        // epilogue: bias + clamp + GLU -> act (granule-packed, k-dim = f)
        char* atile = act + ((size_t)(e * 8 + rt)) * 262144;
        #pragma unroll
        for (int j = 0; j < 4; ++j) {
            int f = ct * 128 + wc * 64 + j * 16 + l15;
            float bgb = gub[(size_t)e * 2048 + 2 * f];
            float bub = gub[(size_t)e * 2048 + 2 * f + 1];
            int tt = f >> 5, kq = (f & 31) >> 3, ke = f & 7;
            #pragma unroll
            for (int m = 0; m < 4; ++m) {
                int rbase = wr * 64 + m * 16 + l4 * 4;
                #pragma unroll
                for (int reg = 0; reg < 4; ++reg) {
                    int r = rbase + reg;
                    if (r >= rows_here) continue;
                    float g = accg[m][j][reg] + bgb;
                    float u = accu[m][j][reg] + bub;
                    g = fminf(g, 7.0f);
                    u = fminf(fmaxf(u, -7.0f), 7.0f);
                    float glu = g / (1.0f + __expf(-1.702f * g));
                    float a = (u + 1.0f) * glu;
                    *(ushort*)(atile + (size_t)tt * 8192 + r * 64 +
                               ((kq ^ ((r >> 1) & 3)) * 16) + ke * 2) = (ushort)bf16r(a);
                }
            }
        }
    }
}

// ---------------- down MFMA GEMM: persistent work-stealing -> eout ----------------
__global__ __launch_bounds__(256, 4) void down_mfma(
    const char* __restrict__ act, const char* __restrict__ wbuf,
    const float* __restrict__ db, const int* __restrict__ counts,
    const int* __restrict__ tile_list, int* __restrict__ meta,
    ushort* __restrict__ eout)
{
    __shared__ char AsB[2][8192];
    __shared__ char BsB[2][8192];
    __shared__ int s_tk;

    const int tid = threadIdx.x;
    const int lane = tid & 63, wid = tid >> 6;
    const int wr = wid >> 1, wc = wid & 1;
    const int l15 = lane & 15, l4 = lane >> 4;
    const int nw = meta[0] * 8;

    for (;;) {
        if (tid == 0) s_tk = atomicAdd(&meta[2], 1);
        __syncthreads();
        const int tk = s_tk;
        if (tk >= nw) break;
        const int pr = tile_list[tk >> 3];
        const int e = pr >> 3, rt = pr & 7, ct = tk & 7;

        const int n = counts[e];
        const int row0 = rt * 128;
        const int rows_here = min(128, n - row0);
        const int c0 = ct * 128;

        const char* atile = act + ((size_t)(e * 8 + rt)) * 262144;
        const char* btile = wbuf + ((size_t)(e * 8 + ct) * 32) * 8192;

        f32x4 acc[4][4];
        #pragma unroll
        for (int m = 0; m < 4; m++)
            #pragma unroll
            for (int j = 0; j < 4; j++) acc[m][j] = (f32x4)0.f;

        auto stage = [&](int buf, int t) {
            const char* sa = atile + (size_t)t * 8192 + tid * 16;
            GLD16(sa, AsB[buf] + tid * 16);
            GLD16(sa + 4096, AsB[buf] + 4096 + tid * 16);
            const char* sb = btile + (size_t)t * 8192 + tid * 16;
            GLD16(sb, BsB[buf] + tid * 16);
            GLD16(sb + 4096, BsB[buf] + 4096 + tid * 16);
        };

        stage(0, 0);
        __syncthreads();
        int cur = 0;
        for (int t = 0; t < 32; ++t) {
            if (t < 31) stage(cur ^ 1, t + 1);

            short8v afr[4];
            #pragma unroll
            for (int m = 0; m < 4; ++m) {
                int row = wr * 64 + m * 16 + l15;
                afr[m] = *(short8v*)(AsB[cur] + row * 64 + ((l4 ^ ((row >> 1) & 3)) * 16));
            }
            __builtin_amdgcn_s_setprio(1);
            #pragma unroll
            for (int j = 0; j < 4; ++j) {
                int nn = wc * 64 + j * 16 + l15;
                short8v b8 = *(short8v*)(BsB[cur] + l4 * 2048 + nn * 16);
                #pragma unroll
                for (int m = 0; m < 4; ++m)
                    acc[m][j] = __builtin_amdgcn_mfma_f32_16x16x32_bf16(afr[m], b8, acc[m][j], 0, 0, 0);
            }
            __builtin_amdgcn_s_setprio(0);
            __syncthreads();
            cur ^= 1;
        }

        // epilogue: bias, store bf16 eout rows
        #pragma unroll
        for (int j = 0; j < 4; ++j) {
            int col = c0 + wc * 64 + j * 16 + l15;
            float bias = db[(size_t)e * H_DIM + col];
            #pragma unroll
            for (int m = 0; m < 4; ++m) {
                int rbase = wr * 64 + m * 16 + l4 * 4;
                #pragma unroll
                for (int reg = 0; reg < 4; ++reg) {
                    int r = rbase + reg;
                    if (r >= rows_here) continue;
                    eout[((size_t)e * CAP + row0 + r) * H_DIM + col] =
                        (ushort)bf16r(acc[m][j][reg] + bias);
                }
            }
        }
    }
}

// ---------------- finalize: out[t] = sum_k w_k * eout[e_k, slot_k] ----------------
__global__ __launch_bounds__(256) void finalize_kernel(
    const ushort* __restrict__ eout, const int* __restrict__ flat_e,
    const float* __restrict__ flat_w, const int* __restrict__ pair_slot,
    float* __restrict__ out)
{
    const int t = blockIdx.x;
    const int c = threadIdx.x * 4;
    float a0 = 0.f, a1 = 0.f, a2 = 0.f, a3 = 0.f;
    #pragma unroll
    for (int k = 0; k < TOPK; ++k) {
        int p = t * TOPK + k;
        int s = pair_slot[p];
        if (s < 0) continue;
        int e = flat_e[p];
        float w = flat_w[p];
        const ushort* row = eout + ((size_t)e * CAP + s) * H_DIM + c;
        ushort4 v = *(const ushort4*)row;
        a0 += w * bf16_bits_to_f32(v.x);
        a1 += w * bf16_bits_to_f32(v.y);
        a2 += w * bf16_bits_to_f32(v.z);
        a3 += w * bf16_bits_to_f32(v.w);
    }
    *(float4*)(out + (size_t)t * H_DIM + c) = make_float4(a0, a1, a2, a3);
}

extern "C" void kernel_launch(void* const* d_in, const int* in_sizes, int n_in,
                              void* d_out, int out_size, void* d_ws, size_t ws_size,
                              hipStream_t stream) {
    const float* x   = (const float*)d_in[0];
    const float* rw  = (const float*)d_in[1];
    const float* rb  = (const float*)d_in[2];
    const float* wgu = (const float*)d_in[3];
    const float* gub = (const float*)d_in[4];
    const float* wd  = (const float*)d_in[5];
    const float* db  = (const float*)d_in[6];

    float* out    = (float*)d_out;
    float* scores = out + (size_t)T_TOK * H_DIM;

    char* ws = (char*)d_ws;
    char* xbuf = ws;                       // 64 MB granule-packed bf16 (overlay eout)
    ushort* eout = (ushort*)ws;
    size_t off = (size_t)E_EXP * CAP * H_DIM * 2;
    char* act     = ws + off;  off += (size_t)E_EXP * CAP * H_DIM * 2;  // 64 MB
    char* wbuf_gu = ws + off;  off += (size_t)E_EXP * 8 * 524288;       // 128 MB
    char* wbuf_dn = ws + off;  off += (size_t)E_EXP * 8 * 32 * 8192;    // 64 MB
    int*   flat_e     = (int*)(ws + off);   off += PAIRS * 4;
    float* flat_w     = (float*)(ws + off); off += PAIRS * 4;
    int*   slot_token = (int*)(ws + off);   off += E_EXP * CAP * 4;
    float* slot_w     = (float*)(ws + off); off += E_EXP * CAP * 4;
    int*   pair_slot  = (int*)(ws + off);   off += PAIRS * 4;
    int*   counts     = (int*)(ws + off);   off += E_EXP * 4;
    int*   tile_list  = (int*)(ws + off);   off += 256 * 4;
    int*   meta       = (int*)(ws + off);   off += 4 * 4;
    (void)ws_size; (void)out_size; (void)n_in; (void)in_sizes; (void)slot_w;

    hipLaunchKernelGGL(router_kernel, dim3(T_TOK), dim3(256), 0, stream,
                       x, rw, rb, scores, flat_e, flat_w);
    hipLaunchKernelGGL(scan_kernel, dim3(1), dim3(256), 0, stream,
                       flat_e, flat_w, slot_token, slot_w, pair_slot, counts,
                       tile_list, meta);
    hipLaunchKernelGGL(stage_tokens, dim3(8, E_EXP), dim3(256), 0, stream,
                       x, slot_token, counts, xbuf);
    hipLaunchKernelGGL(conv_gu, dim3(8, 4, E_EXP), dim3(256), 0, stream, wgu, wbuf_gu);
    hipLaunchKernelGGL(conv_dn, dim3(8, 8, E_EXP), dim3(256), 0, stream, wd, wbuf_dn);
    hipLaunchKernelGGL(gateup_mfma, dim3(512), dim3(256), 0, stream,
                       xbuf, wbuf_gu, gub, counts, tile_list, meta, act);
    hipLaunchKernelGGL(down_mfma, dim3(1024), dim3(256), 0, stream,
                       act, wbuf_dn, db, counts, tile_list, meta, eout);
    hipLaunchKernelGGL(finalize_kernel, dim3(T_TOK), dim3(256), 0, stream,
                       eout, flat_e, flat_w, pair_slot, out);
}

// Round 9
// 530.279 us; speedup vs baseline: 1.0236x; 1.0236x over previous
//
#include <hip/hip_runtime.h>
#include <hip/hip_bf16.h>

#define T_TOK 4096
#define H_DIM 1024
#define E_EXP 32
#define TOPK 4
#define CAP 1024
#define PAIRS (T_TOK*TOPK)

typedef __attribute__((ext_vector_type(8))) short short8v;
typedef __attribute__((ext_vector_type(4))) float f32x4;
typedef unsigned long long u64;
typedef unsigned short ushort;

__device__ __forceinline__ float bf16_bits_to_f32(ushort h) {
    return __uint_as_float(((unsigned)h) << 16);
}
__device__ __forceinline__ unsigned bf16r(float f) {
    unsigned u = __float_as_uint(f);
    return ((u + 0x7fffu + ((u >> 16) & 1u)) >> 16) & 0xffffu;
}
// v_cvt_pk_bf16_f32: D[15:0]=bf16(a), D[31:16]=bf16(b)
__device__ __forceinline__ unsigned cvt2(float a, float b) {
    unsigned r;
    asm("v_cvt_pk_bf16_f32 %0, %1, %2" : "=v"(r) : "v"(a), "v"(b));
    return r;
}

#define GLD16(gsrc, ldst) \
    __builtin_amdgcn_global_load_lds( \
        (const __attribute__((address_space(1))) unsigned*)(gsrc), \
        (__attribute__((address_space(3))) unsigned*)(ldst), 16, 0, 0)

#define WAIT_VM4() asm volatile("s_waitcnt vmcnt(4)" ::: "memory")
#define WAIT_VM0() asm volatile("s_waitcnt vmcnt(0)" ::: "memory")
#define SCHEDB()   __builtin_amdgcn_sched_barrier(0)
#define BARRIER()  __builtin_amdgcn_s_barrier()

// ---------------- router ----------------
__global__ __launch_bounds__(256) void router_kernel(
    const float* __restrict__ x, const float* __restrict__ rw,
    const float* __restrict__ rb, float* __restrict__ scores,
    int* __restrict__ flat_e, float* __restrict__ flat_w)
{
    __shared__ float xs[H_DIM];
    __shared__ float lg[E_EXP];
    __shared__ float sw[TOPK];
    __shared__ int   se[TOPK];
    const int t = blockIdx.x;
    const int tid = threadIdx.x;

    for (int i = tid; i < H_DIM; i += 256) xs[i] = x[(size_t)t * H_DIM + i];
    __syncthreads();

    const int e = tid >> 3, l8 = tid & 7;
    float partial = 0.f;
    const float* wr = rw + (size_t)e * H_DIM;
    for (int h = l8; h < H_DIM; h += 8) partial += xs[h] * wr[h];
    partial += __shfl_xor(partial, 1);
    partial += __shfl_xor(partial, 2);
    partial += __shfl_xor(partial, 4);
    if (l8 == 0) lg[e] = partial + rb[e];
    __syncthreads();

    if (tid == 0) {
        unsigned used = 0;
        float bv[TOPK]; int bi[TOPK];
        #pragma unroll
        for (int j = 0; j < TOPK; j++) {
            float best = -1e30f; int bid = -1;
            for (int q = 0; q < E_EXP; q++) {
                if (used & (1u << q)) continue;
                if (lg[q] > best) { best = lg[q]; bid = q; }
            }
            used |= 1u << bid;
            bv[j] = best; bi[j] = bid;
        }
        const float m = bv[0];
        float s = 0.f; float w[TOPK];
        #pragma unroll
        for (int j = 0; j < TOPK; j++) { w[j] = expf(bv[j] - m); s += w[j]; }
        const float inv = 1.f / s;
        #pragma unroll
        for (int j = 0; j < TOPK; j++) { sw[j] = w[j] * inv; se[j] = bi[j]; }
    }
    __syncthreads();

    if (tid < E_EXP) {
        float v = 0.f;
        #pragma unroll
        for (int j = 0; j < TOPK; j++) if (se[j] == tid) v = sw[j];
        scores[(size_t)t * E_EXP + tid] = v;
    }
    if (tid < TOPK) {
        flat_e[t * TOPK + tid] = se[tid];
        flat_w[t * TOPK + tid] = sw[tid];
    }
}

// ---------------- deterministic rank scan ----------------
__global__ __launch_bounds__(256) void scan_kernel(
    const int* __restrict__ flat_e, const float* __restrict__ flat_w,
    int* __restrict__ slot_token, float* __restrict__ slot_w,
    int* __restrict__ pair_slot, int* __restrict__ counts)
{
    __shared__ int cnt[256 * E_EXP];
    const int tid = threadIdx.x;
    for (int e = 0; e < E_EXP; e++) cnt[tid * E_EXP + e] = 0;
    __syncthreads();
    const int base = tid * (PAIRS / 256);
    for (int i = 0; i < PAIRS / 256; i++) {
        int e = flat_e[base + i];
        cnt[tid * E_EXP + e]++;
    }
    __syncthreads();
    if (tid < E_EXP) {
        int run = 0;
        for (int i = 0; i < 256; i++) {
            int idx = i * E_EXP + tid;
            int v = cnt[idx];
            cnt[idx] = run;
            run += v;
        }
        counts[tid] = min(run, CAP);
    }
    __syncthreads();
    for (int i = 0; i < PAIRS / 256; i++) {
        int p = base + i;
        int e = flat_e[p];
        int r = cnt[tid * E_EXP + e]++;
        if (r < CAP) {
            slot_token[e * CAP + r] = p >> 2;
            slot_w[e * CAP + r] = flat_w[p];
            pair_slot[p] = r;
        } else {
            pair_slot[p] = -1;
        }
    }
}

// ---------------- stage tokens: gather x -> granule-packed bf16 xbuf ----------------
__global__ __launch_bounds__(256) void stage_tokens(
    const float* __restrict__ x, const int* __restrict__ slot_token,
    const int* __restrict__ counts, char* __restrict__ xbuf)
{
    const int e = blockIdx.y, rt = blockIdx.x;
    const int n = counts[e];
    const int row0 = rt * 128;
    if (row0 >= n) return;
    const int rows_here = min(128, n - row0);
    const int lane = threadIdx.x & 63, wv = threadIdx.x >> 6;
    char* tb = xbuf + ((size_t)(e * 8 + rt)) * 262144;

    for (int r = wv; r < rows_here; r += 4) {
        const float* xr = x + (size_t)slot_token[e * CAP + row0 + r] * H_DIM;
        const int s = (r >> 1) & 3;
        #pragma unroll
        for (int half = 0; half < 2; ++half) {
            int gi = half * 64 + lane;
            float4 a = *(const float4*)(xr + gi * 8);
            float4 b = *(const float4*)(xr + gi * 8 + 4);
            uint4 w;
            w.x = cvt2(a.x, a.y); w.y = cvt2(a.z, a.w);
            w.z = cvt2(b.x, b.y); w.w = cvt2(b.z, b.w);
            int t = gi >> 2, kq = gi & 3;
            *(uint4*)(tb + (size_t)t * 8192 + r * 64 + ((kq ^ s) * 16)) = w;
        }
    }
}

// ---------------- convert gate_up weights -> packed bf16 (128 gu-col panels) ----------------
// per (e, ct 0..15): 32 K-tiles of 8KB; g granule at kq*1024 + f*16, u at +4096
__global__ __launch_bounds__(256) void conv_gu(
    const float* __restrict__ wgu, char* __restrict__ wbuf)
{
    const int ct = blockIdx.x;      // 0..15
    const int tseg = blockIdx.y;    // 0..3
    const int e = blockIdx.z;       // 0..31
    const int lane = threadIdx.x & 63, wv = threadIdx.x >> 6;
    char* dst_base = wbuf + ((size_t)(e * 16 + ct) * 32) * 8192;
    #pragma unroll
    for (int i = 0; i < 2; ++i) {
        const int t = tseg * 8 + wv * 2 + i;
        const float* src = wgu + ((size_t)e * 1024 + t * 32) * 2048 + ct * 128 + 2 * lane;
        float2 v[32];
        #pragma unroll
        for (int k = 0; k < 32; ++k) v[k] = *(const float2*)(src + (size_t)k * 2048);
        char* dst = dst_base + (size_t)t * 8192 + lane * 16;
        #pragma unroll
        for (int kq = 0; kq < 4; ++kq) {
            uint4 g, u;
            g.x = cvt2(v[kq*8+0].x, v[kq*8+1].x); g.y = cvt2(v[kq*8+2].x, v[kq*8+3].x);
            g.z = cvt2(v[kq*8+4].x, v[kq*8+5].x); g.w = cvt2(v[kq*8+6].x, v[kq*8+7].x);
            u.x = cvt2(v[kq*8+0].y, v[kq*8+1].y); u.y = cvt2(v[kq*8+2].y, v[kq*8+3].y);
            u.z = cvt2(v[kq*8+4].y, v[kq*8+5].y); u.w = cvt2(v[kq*8+6].y, v[kq*8+7].y);
            *(uint4*)(dst + kq * 1024) = g;
            *(uint4*)(dst + 4096 + kq * 1024) = u;
        }
    }
}

// ---------------- convert down weights -> packed bf16 ----------------
// per (e, ct 0..7): 32 K-tiles of 8KB; granule at kq*2048 + nn*16
__global__ __launch_bounds__(256) void conv_dn(
    const float* __restrict__ wd, char* __restrict__ wbuf)
{
    const int ct = blockIdx.x;   // 0..7
    const int tseg = blockIdx.y; // 0..7
    const int e = blockIdx.z;    // 0..31
    const int lane = threadIdx.x & 63, wv = threadIdx.x >> 6;
    const int t = tseg * 4 + wv;
    const float* src = wd + ((size_t)e * 1024 + t * 32) * 1024 + ct * 128 + 2 * lane;
    float2 v[32];
    #pragma unroll
    for (int k = 0; k < 32; ++k) v[k] = *(const float2*)(src + (size_t)k * 1024);
    char* dst = wbuf + (((size_t)(e * 8 + ct) * 32) + t) * 8192 + (2 * lane) * 16;
    #pragma unroll
    for (int kq = 0; kq < 4; ++kq) {
        uint4 g0, g1;
        g0.x = cvt2(v[kq*8+0].x, v[kq*8+1].x); g0.y = cvt2(v[kq*8+2].x, v[kq*8+3].x);
        g0.z = cvt2(v[kq*8+4].x, v[kq*8+5].x); g0.w = cvt2(v[kq*8+6].x, v[kq*8+7].x);
        g1.x = cvt2(v[kq*8+0].y, v[kq*8+1].y); g1.y = cvt2(v[kq*8+2].y, v[kq*8+3].y);
        g1.z = cvt2(v[kq*8+4].y, v[kq*8+5].y); g1.w = cvt2(v[kq*8+6].y, v[kq*8+7].y);
        *(uint4*)(dst + kq * 2048) = g0;
        *(uint4*)(dst + kq * 2048 + 16) = g1;
    }
}

// ---------------- gate_up MFMA GEMM: depth-3 counted-vmcnt pipeline ----------------
__global__ __launch_bounds__(256, 3) void gateup_mfma(
    const char* __restrict__ xbuf, const char* __restrict__ wbuf,
    const float* __restrict__ gub, const int* __restrict__ counts,
    char* __restrict__ act)
{
    const int lin = blockIdx.x;             // 4096
    const int xcd = lin & 7, slot = lin >> 3;
    const int gg = (slot >> 3) * 8 + xcd;   // 0..511
    const int rt = slot & 7;
    const int e = gg >> 4, ct = gg & 15;

    const int n = counts[e];
    const int row0 = rt * 128;
    if (row0 >= n) return;
    const int rows_here = min(128, n - row0);
    const int c0f = ct * 64;

    __shared__ char AsB[3][8192];
    __shared__ char BsB[3][8192];

    const int tid = threadIdx.x;
    const int lane = tid & 63, wid = tid >> 6;
    const int wr = wid >> 1, wc = wid & 1;
    const int l15 = lane & 15, l4 = lane >> 4;

    const char* xtile = xbuf + ((size_t)(e * 8 + rt)) * 262144;
    const char* btile = wbuf + ((size_t)(e * 16 + ct) * 32) * 8192;

    f32x4 accg[4][2], accu[4][2];
    #pragma unroll
    for (int m = 0; m < 4; m++)
        #pragma unroll
        for (int j = 0; j < 2; j++) { accg[m][j] = (f32x4)0.f; accu[m][j] = (f32x4)0.f; }

    auto stage = [&](int buf, int t) {
        const char* sa = xtile + (size_t)t * 8192 + tid * 16;
        GLD16(sa, AsB[buf] + tid * 16);
        GLD16(sa + 4096, AsB[buf] + 4096 + tid * 16);
        const char* sb = btile + (size_t)t * 8192 + tid * 16;
        GLD16(sb, BsB[buf] + tid * 16);
        GLD16(sb + 4096, BsB[buf] + 4096 + tid * 16);
    };

    // prologue: buffers 0,1 in flight (8 loads); wait for buf0 (4 remain)
    stage(0, 0);
    stage(1, 1);
    WAIT_VM4(); SCHEDB();
    BARRIER(); SCHEDB();

    int cur = 0, dst = 2;
    for (int t = 0; t < 32; ++t) {
        // issue t+2 first: flies under this iter's MFMA + next iter's
        if (t + 2 < 32) stage(dst, t + 2);

        short8v afr[4];
        #pragma unroll
        for (int m = 0; m < 4; ++m) {
            int row = wr * 64 + m * 16 + l15;
            afr[m] = *(short8v*)(AsB[cur] + row * 64 + ((l4 ^ ((row >> 1) & 3)) * 16));
        }
        __builtin_amdgcn_s_setprio(1);
        #pragma unroll
        for (int j = 0; j < 2; ++j) {
            int fl = wc * 32 + j * 16 + l15;
            short8v bg8 = *(short8v*)(BsB[cur] + l4 * 1024 + fl * 16);
            short8v bu8 = *(short8v*)(BsB[cur] + 4096 + l4 * 1024 + fl * 16);
            #pragma unroll
            for (int m = 0; m < 4; ++m) {
                accg[m][j] = __builtin_amdgcn_mfma_f32_16x16x32_bf16(afr[m], bg8, accg[m][j], 0, 0, 0);
                accu[m][j] = __builtin_amdgcn_mfma_f32_16x16x32_bf16(afr[m], bu8, accu[m][j], 0, 0, 0);
            }
        }
        __builtin_amdgcn_s_setprio(0);

        if (t + 2 < 32) { WAIT_VM4(); }          // buf[t+1] done, t+2 in flight
        else if (t + 1 < 32) { WAIT_VM0(); }     // drain last stage
        SCHEDB();
        if (t + 1 < 32) { BARRIER(); SCHEDB(); }
        cur = (cur == 2) ? 0 : cur + 1;
        dst = (dst == 2) ? 0 : dst + 1;
    }

    // epilogue: bias + clamp + GLU -> act (granule-packed, k-dim = f)
    char* atile = act + ((size_t)(e * 8 + rt)) * 262144;
    #pragma unroll
    for (int j = 0; j < 2; ++j) {
        int f = c0f + wc * 32 + j * 16 + l15;
        float bgb = gub[(size_t)e * 2048 + 2 * f];
        float bub = gub[(size_t)e * 2048 + 2 * f + 1];
        int tt = f >> 5, kq = (f & 31) >> 3, ke = f & 7;
        #pragma unroll
        for (int m = 0; m < 4; ++m) {
            int rbase = wr * 64 + m * 16 + l4 * 4;
            #pragma unroll
            for (int reg = 0; reg < 4; ++reg) {
                int r = rbase + reg;
                if (r >= rows_here) continue;
                float g = accg[m][j][reg] + bgb;
                float u = accu[m][j][reg] + bub;
                g = fminf(g, 7.0f);
                u = fminf(fmaxf(u, -7.0f), 7.0f);
                float glu = g / (1.0f + __expf(-1.702f * g));
                float a = (u + 1.0f) * glu;
                *(ushort*)(atile + (size_t)tt * 8192 + r * 64 +
                           ((kq ^ ((r >> 1) & 3)) * 16) + ke * 2) = (ushort)bf16r(a);
            }
        }
    }
}

// ---------------- down MFMA GEMM: depth-3 counted-vmcnt pipeline -> eout ----------------
__global__ __launch_bounds__(256, 3) void down_mfma(
    const char* __restrict__ act, const char* __restrict__ wbuf,
    const float* __restrict__ db, const int* __restrict__ counts,
    ushort* __restrict__ eout)
{
    const int lin = blockIdx.x;             // 2048
    const int xcd = lin & 7, slot = lin >> 3;
    const int gg = (slot >> 3) * 8 + xcd;   // 0..255
    const int rt = slot & 7;
    const int e = gg >> 3, ct = gg & 7;

    const int n = counts[e];
    const int row0 = rt * 128;
    if (row0 >= n) return;
    const int rows_here = min(128, n - row0);
    const int c0 = ct * 128;

    __shared__ char AsB[3][8192];
    __shared__ char BsB[3][8192];

    const int tid = threadIdx.x;
    const int lane = tid & 63, wid = tid >> 6;
    const int wr = wid >> 1, wc = wid & 1;
    const int l15 = lane & 15, l4 = lane >> 4;

    const char* atile = act + ((size_t)(e * 8 + rt)) * 262144;
    const char* btile = wbuf + ((size_t)(e * 8 + ct) * 32) * 8192;

    f32x4 acc[4][4];
    #pragma unroll
    for (int m = 0; m < 4; m++)
        #pragma unroll
        for (int j = 0; j < 4; j++) acc[m][j] = (f32x4)0.f;

    auto stage = [&](int buf, int t) {
        const char* sa = atile + (size_t)t * 8192 + tid * 16;
        GLD16(sa, AsB[buf] + tid * 16);
        GLD16(sa + 4096, AsB[buf] + 4096 + tid * 16);
        const char* sb = btile + (size_t)t * 8192 + tid * 16;
        GLD16(sb, BsB[buf] + tid * 16);
        GLD16(sb + 4096, BsB[buf] + 4096 + tid * 16);
    };

    stage(0, 0);
    stage(1, 1);
    WAIT_VM4(); SCHEDB();
    BARRIER(); SCHEDB();

    int cur = 0, dst = 2;
    for (int t = 0; t < 32; ++t) {
        if (t + 2 < 32) stage(dst, t + 2);

        short8v afr[4];
        #pragma unroll
        for (int m = 0; m < 4; ++m) {
            int row = wr * 64 + m * 16 + l15;
            afr[m] = *(short8v*)(AsB[cur] + row * 64 + ((l4 ^ ((row >> 1) & 3)) * 16));
        }
        __builtin_amdgcn_s_setprio(1);
        #pragma unroll
        for (int j = 0; j < 4; ++j) {
            int nn = wc * 64 + j * 16 + l15;
            short8v b8 = *(short8v*)(BsB[cur] + l4 * 2048 + nn * 16);
            #pragma unroll
            for (int m = 0; m < 4; ++m)
                acc[m][j] = __builtin_amdgcn_mfma_f32_16x16x32_bf16(afr[m], b8, acc[m][j], 0, 0, 0);
        }
        __builtin_amdgcn_s_setprio(0);

        if (t + 2 < 32) { WAIT_VM4(); }
        else if (t + 1 < 32) { WAIT_VM0(); }
        SCHEDB();
        if (t + 1 < 32) { BARRIER(); SCHEDB(); }
        cur = (cur == 2) ? 0 : cur + 1;
        dst = (dst == 2) ? 0 : dst + 1;
    }

    // epilogue: bias, store bf16 eout rows
    #pragma unroll
    for (int j = 0; j < 4; ++j) {
        int col = c0 + wc * 64 + j * 16 + l15;
        float bias = db[(size_t)e * H_DIM + col];
        #pragma unroll
        for (int m = 0; m < 4; ++m) {
            int rbase = wr * 64 + m * 16 + l4 * 4;
            #pragma unroll
            for (int reg = 0; reg < 4; ++reg) {
                int r = rbase + reg;
                if (r >= rows_here) continue;
                eout[((size_t)e * CAP + row0 + r) * H_DIM + col] =
                    (ushort)bf16r(acc[m][j][reg] + bias);
            }
        }
    }
}

// ---------------- finalize: out[t] = sum_k w_k * eout[e_k, slot_k] ----------------
__global__ __launch_bounds__(256) void finalize_kernel(
    const ushort* __restrict__ eout, const int* __restrict__ flat_e,
    const float* __restrict__ flat_w, const int* __restrict__ pair_slot,
    float* __restrict__ out)
{
    const int t = blockIdx.x;
    const int c = threadIdx.x * 4;
    float a0 = 0.f, a1 = 0.f, a2 = 0.f, a3 = 0.f;
    #pragma unroll
    for (int k = 0; k < TOPK; ++k) {
        int p = t * TOPK + k;
        int s = pair_slot[p];
        if (s < 0) continue;
        int e = flat_e[p];
        float w = flat_w[p];
        const ushort* row = eout + ((size_t)e * CAP + s) * H_DIM + c;
        ushort4 v = *(const ushort4*)row;
        a0 += w * bf16_bits_to_f32(v.x);
        a1 += w * bf16_bits_to_f32(v.y);
        a2 += w * bf16_bits_to_f32(v.z);
        a3 += w * bf16_bits_to_f32(v.w);
    }
    *(float4*)(out + (size_t)t * H_DIM + c) = make_float4(a0, a1, a2, a3);
}

extern "C" void kernel_launch(void* const* d_in, const int* in_sizes, int n_in,
                              void* d_out, int out_size, void* d_ws, size_t ws_size,
                              hipStream_t stream) {
    const float* x   = (const float*)d_in[0];
    const float* rw  = (const float*)d_in[1];
    const float* rb  = (const float*)d_in[2];
    const float* wgu = (const float*)d_in[3];
    const float* gub = (const float*)d_in[4];
    const float* wd  = (const float*)d_in[5];
    const float* db  = (const float*)d_in[6];

    float* out    = (float*)d_out;
    float* scores = out + (size_t)T_TOK * H_DIM;

    char* ws = (char*)d_ws;
    char* xbuf = ws;                       // 64 MB granule-packed bf16 (overlay eout)
    ushort* eout = (ushort*)ws;
    size_t off = (size_t)E_EXP * CAP * H_DIM * 2;
    char* act     = ws + off;  off += (size_t)E_EXP * CAP * H_DIM * 2;  // 64 MB
    char* wbuf_gu = ws + off;  off += (size_t)E_EXP * 16 * 32 * 8192;   // 128 MB
    char* wbuf_dn = ws + off;  off += (size_t)E_EXP * 8 * 32 * 8192;    // 64 MB
    int*   flat_e     = (int*)(ws + off);   off += PAIRS * 4;
    float* flat_w     = (float*)(ws + off); off += PAIRS * 4;
    int*   slot_token = (int*)(ws + off);   off += E_EXP * CAP * 4;
    float* slot_w     = (float*)(ws + off); off += E_EXP * CAP * 4;
    int*   pair_slot  = (int*)(ws + off);   off += PAIRS * 4;
    int*   counts     = (int*)(ws + off);   off += E_EXP * 4;
    (void)ws_size; (void)out_size; (void)n_in; (void)in_sizes; (void)slot_w;

    hipLaunchKernelGGL(router_kernel, dim3(T_TOK), dim3(256), 0, stream,
                       x, rw, rb, scores, flat_e, flat_w);
    hipLaunchKernelGGL(scan_kernel, dim3(1), dim3(256), 0, stream,
                       flat_e, flat_w, slot_token, slot_w, pair_slot, counts);
    hipLaunchKernelGGL(stage_tokens, dim3(8, E_EXP), dim3(256), 0, stream,
                       x, slot_token, counts, xbuf);
    hipLaunchKernelGGL(conv_gu, dim3(16, 4, E_EXP), dim3(256), 0, stream, wgu, wbuf_gu);
    hipLaunchKernelGGL(conv_dn, dim3(8, 8, E_EXP), dim3(256), 0, stream, wd, wbuf_dn);
    hipLaunchKernelGGL(gateup_mfma, dim3(4096), dim3(256), 0, stream,
                       xbuf, wbuf_gu, gub, counts, act);
    hipLaunchKernelGGL(down_mfma, dim3(2048), dim3(256), 0, stream,
                       act, wbuf_dn, db, counts, eout);
    hipLaunchKernelGGL(finalize_kernel, dim3(T_TOK), dim3(256), 0, stream,
                       eout, flat_e, flat_w, pair_slot, out);
}

// Round 10
// 507.457 us; speedup vs baseline: 1.0697x; 1.0450x over previous
//
#include <hip/hip_runtime.h>
#include <hip/hip_bf16.h>

#define T_TOK 4096
#define H_DIM 1024
#define E_EXP 32
#define TOPK 4
#define CAP 1024
#define PAIRS (T_TOK*TOPK)

typedef __attribute__((ext_vector_type(8))) short short8v;
typedef __attribute__((ext_vector_type(4))) float f32x4;
typedef unsigned long long u64;
typedef unsigned short ushort;

__device__ __forceinline__ float bf16_bits_to_f32(ushort h) {
    return __uint_as_float(((unsigned)h) << 16);
}
__device__ __forceinline__ unsigned bf16r(float f) {
    unsigned u = __float_as_uint(f);
    return ((u + 0x7fffu + ((u >> 16) & 1u)) >> 16) & 0xffffu;
}
// v_cvt_pk_bf16_f32: D[15:0]=bf16(a), D[31:16]=bf16(b)
__device__ __forceinline__ unsigned cvt2(float a, float b) {
    unsigned r;
    asm("v_cvt_pk_bf16_f32 %0, %1, %2" : "=v"(r) : "v"(a), "v"(b));
    return r;
}

#define GLD16(gsrc, ldst) \
    __builtin_amdgcn_global_load_lds( \
        (const __attribute__((address_space(1))) unsigned*)(gsrc), \
        (__attribute__((address_space(3))) unsigned*)(ldst), 16, 0, 0)

#define WAIT_VM1() asm volatile("s_waitcnt vmcnt(1)" ::: "memory")
#define WAIT_VM0() asm volatile("s_waitcnt vmcnt(0)" ::: "memory")
#define SCHEDB()   __builtin_amdgcn_sched_barrier(0)
#define BARRIER()  __builtin_amdgcn_s_barrier()

// ---------------- router: 8 tokens/block, single rw pass ----------------
__global__ __launch_bounds__(256) void router_kernel(
    const float* __restrict__ x, const float* __restrict__ rw,
    const float* __restrict__ rb, float* __restrict__ scores,
    int* __restrict__ flat_e, float* __restrict__ flat_w)
{
    __shared__ float xs[8][H_DIM];   // 32 KB
    __shared__ float lg[8][E_EXP];
    const int t0 = blockIdx.x * 8;
    const int tid = threadIdx.x;

    for (int i = tid; i < 2048; i += 256) {   // 8 rows x 256 float4
        int row = i >> 8, c4 = i & 255;
        *(float4*)&xs[row][c4 * 4] =
            *(const float4*)(x + (size_t)(t0 + row) * H_DIM + c4 * 4);
    }
    __syncthreads();

    const int e = tid >> 3, l8 = tid & 7;
    float part[8];
    #pragma unroll
    for (int tt = 0; tt < 8; ++tt) part[tt] = 0.f;
    const float* wrow = rw + (size_t)e * H_DIM;
    for (int h = l8; h < H_DIM; h += 8) {
        float w = wrow[h];
        #pragma unroll
        for (int tt = 0; tt < 8; ++tt) part[tt] = fmaf(xs[tt][h], w, part[tt]);
    }
    #pragma unroll
    for (int tt = 0; tt < 8; ++tt) {
        float v = part[tt];
        v += __shfl_xor(v, 1);
        v += __shfl_xor(v, 2);
        v += __shfl_xor(v, 4);
        if (l8 == 0) lg[tt][e] = v + rb[e];
    }
    __syncthreads();

    if (tid < 8) {
        const int tt = tid, t = t0 + tt;
        unsigned used = 0;
        float bv[TOPK]; int bi[TOPK];
        #pragma unroll
        for (int j = 0; j < TOPK; j++) {
            float best = -1e30f; int bid = -1;
            for (int q = 0; q < E_EXP; q++) {
                if (used & (1u << q)) continue;
                if (lg[tt][q] > best) { best = lg[tt][q]; bid = q; }
            }
            used |= 1u << bid;
            bv[j] = best; bi[j] = bid;
        }
        const float m = bv[0];
        float s = 0.f; float w[TOPK];
        #pragma unroll
        for (int j = 0; j < TOPK; j++) { w[j] = expf(bv[j] - m); s += w[j]; }
        const float inv = 1.f / s;
        #pragma unroll
        for (int j = 0; j < TOPK; j++) w[j] *= inv;
        for (int q = 0; q < E_EXP; ++q) {
            float v = 0.f;
            #pragma unroll
            for (int j = 0; j < TOPK; j++) if (bi[j] == q) v = w[j];
            scores[(size_t)t * E_EXP + q] = v;
        }
        #pragma unroll
        for (int j = 0; j < TOPK; j++) {
            flat_e[t * TOPK + j] = bi[j];
            flat_w[t * TOPK + j] = w[j];
        }
    }
}

// ---------------- deterministic rank scan ----------------
__global__ __launch_bounds__(256) void scan_kernel(
    const int* __restrict__ flat_e, const float* __restrict__ flat_w,
    int* __restrict__ slot_token, float* __restrict__ slot_w,
    int* __restrict__ pair_slot, int* __restrict__ counts)
{
    __shared__ int cnt[256 * E_EXP];
    const int tid = threadIdx.x;
    for (int e = 0; e < E_EXP; e++) cnt[tid * E_EXP + e] = 0;
    __syncthreads();
    const int base = tid * (PAIRS / 256);
    for (int i = 0; i < PAIRS / 256; i++) {
        int e = flat_e[base + i];
        cnt[tid * E_EXP + e]++;
    }
    __syncthreads();
    if (tid < E_EXP) {
        int run = 0;
        for (int i = 0; i < 256; i++) {
            int idx = i * E_EXP + tid;
            int v = cnt[idx];
            cnt[idx] = run;
            run += v;
        }
        counts[tid] = min(run, CAP);
    }
    __syncthreads();
    for (int i = 0; i < PAIRS / 256; i++) {
        int p = base + i;
        int e = flat_e[p];
        int r = cnt[tid * E_EXP + e]++;
        if (r < CAP) {
            slot_token[e * CAP + r] = p >> 2;
            slot_w[e * CAP + r] = flat_w[p];
            pair_slot[p] = r;
        } else {
            pair_slot[p] = -1;
        }
    }
}

// ---------------- stage tokens: gather x -> granule-packed bf16 xbuf ----------------
__global__ __launch_bounds__(256) void stage_tokens(
    const float* __restrict__ x, const int* __restrict__ slot_token,
    const int* __restrict__ counts, char* __restrict__ xbuf)
{
    const int e = blockIdx.y, rt = blockIdx.x;
    const int n = counts[e];
    const int row0 = rt * 128;
    if (row0 >= n) return;
    const int rows_here = min(128, n - row0);
    const int lane = threadIdx.x & 63, wv = threadIdx.x >> 6;
    char* tb = xbuf + ((size_t)(e * 8 + rt)) * 262144;

    for (int r = wv; r < rows_here; r += 4) {
        const float* xr = x + (size_t)slot_token[e * CAP + row0 + r] * H_DIM;
        const int s = (r >> 1) & 3;
        #pragma unroll
        for (int half = 0; half < 2; ++half) {
            int gi = half * 64 + lane;
            float4 a = *(const float4*)(xr + gi * 8);
            float4 b = *(const float4*)(xr + gi * 8 + 4);
            uint4 w;
            w.x = cvt2(a.x, a.y); w.y = cvt2(a.z, a.w);
            w.z = cvt2(b.x, b.y); w.w = cvt2(b.z, b.w);
            int t = gi >> 2, kq = gi & 3;
            *(uint4*)(tb + (size_t)t * 8192 + r * 64 + ((kq ^ s) * 16)) = w;
        }
    }
}

// ---------------- convert down weights -> packed bf16 ----------------
__global__ __launch_bounds__(256) void conv_dn(
    const float* __restrict__ wd, char* __restrict__ wbuf)
{
    const int ct = blockIdx.x;   // 0..7
    const int tseg = blockIdx.y; // 0..7
    const int e = blockIdx.z;    // 0..31
    const int lane = threadIdx.x & 63, wv = threadIdx.x >> 6;
    const int t = tseg * 4 + wv;
    const float* src = wd + ((size_t)e * 1024 + t * 32) * 1024 + ct * 128 + 2 * lane;
    float2 v[32];
    #pragma unroll
    for (int k = 0; k < 32; ++k) v[k] = *(const float2*)(src + (size_t)k * 1024);
    char* dst = wbuf + (((size_t)(e * 8 + ct) * 32) + t) * 8192 + (2 * lane) * 16;
    #pragma unroll
    for (int kq = 0; kq < 4; ++kq) {
        uint4 g0, g1;
        g0.x = cvt2(v[kq*8+0].x, v[kq*8+1].x); g0.y = cvt2(v[kq*8+2].x, v[kq*8+3].x);
        g0.z = cvt2(v[kq*8+4].x, v[kq*8+5].x); g0.w = cvt2(v[kq*8+6].x, v[kq*8+7].x);
        g1.x = cvt2(v[kq*8+0].y, v[kq*8+1].y); g1.y = cvt2(v[kq*8+2].y, v[kq*8+3].y);
        g1.z = cvt2(v[kq*8+4].y, v[kq*8+5].y); g1.w = cvt2(v[kq*8+6].y, v[kq*8+7].y);
        *(uint4*)(dst + kq * 2048) = g0;
        *(uint4*)(dst + kq * 2048 + 16) = g1;
    }
}

// ---------------- gate_up: B-STATIONARY MFMA GEMM ----------------
// block = (e, panel p of 64 gu-cols). Converts fp32 panel -> 128 KB resident
// LDS bf16 once, then loops row-tiles streaming A only (triple-buffered GLD16).
__global__ __launch_bounds__(512, 1) void gateup_mfma(
    const char* __restrict__ xbuf, const float* __restrict__ wgu,
    const float* __restrict__ gub, const int* __restrict__ counts,
    char* __restrict__ act)
{
    extern __shared__ char smem[];
    char* Bg = smem;                  // 64 KB
    char* Bu = smem + 65536;          // 64 KB
    char* As = smem + 131072;         // 3 x 8 KB

    const int lin = blockIdx.x;       // 1024
    const int e = lin >> 5, p = lin & 31;
    const int n = counts[e];
    if (n <= 0) return;
    const int nrt = (n + 127) >> 7;
    const int tid = threadIdx.x;

    // ---- panel load+convert: 64 gu cols [64p,64p+64) x K=1024
    {
        const int f = tid & 31, kc = tid >> 5;   // kc 0..15, 64 K each
        #pragma unroll
        for (int g8 = 0; g8 < 8; ++g8) {
            const int k0 = kc * 64 + g8 * 8;
            const float* s = wgu + ((size_t)e * 1024 + k0) * 2048 + p * 64 + 2 * f;
            float2 v[8];
            #pragma unroll
            for (int i = 0; i < 8; ++i) v[i] = *(const float2*)(s + (size_t)i * 2048);
            uint4 g, u;
            g.x = cvt2(v[0].x, v[1].x); g.y = cvt2(v[2].x, v[3].x);
            g.z = cvt2(v[4].x, v[5].x); g.w = cvt2(v[6].x, v[7].x);
            u.x = cvt2(v[0].y, v[1].y); u.y = cvt2(v[2].y, v[3].y);
            u.z = cvt2(v[4].y, v[5].y); u.w = cvt2(v[6].y, v[7].y);
            const int t = k0 >> 5, kq = (k0 >> 3) & 3;
            const int off = t * 2048 + kq * 512 + ((f ^ (kq << 2)) * 16);
            *(uint4*)(Bg + off) = g;
            *(uint4*)(Bu + off) = u;
        }
    }
    __syncthreads();

    const int lane = tid & 63, wid = tid >> 6;
    const int wr = wid >> 1, wc = wid & 1;       // 4x2 waves: 32 rows x 16 f each
    const int l15 = lane & 15, l4 = lane >> 4;
    const int fl = wc * 16 + l15;                // panel-local f (0..31)
    const int boff = l4 * 512 + ((fl ^ (l4 << 2)) * 16);

    const int fg = p * 32 + fl;                  // global f
    const float bgb = gub[(size_t)e * 2048 + 2 * fg];
    const float bub = gub[(size_t)e * 2048 + 2 * fg + 1];
    const int kq2 = (fg & 31) >> 3, ke = fg & 7; // act granule coords (tt==p)

    for (int rt = 0; rt < nrt; ++rt) {
        const char* xtile = xbuf + ((size_t)(e * 8 + rt)) * 262144;
        const int rows_here = min(128, n - rt * 128);

        f32x4 accg[2], accu[2];
        accg[0] = (f32x4)0.f; accg[1] = (f32x4)0.f;
        accu[0] = (f32x4)0.f; accu[1] = (f32x4)0.f;

        __syncthreads();   // protect As from previous row-tile readers
        GLD16(xtile + tid * 16, As + tid * 16);                  // buf0
        GLD16(xtile + 8192 + tid * 16, As + 8192 + tid * 16);    // buf1
        WAIT_VM1(); SCHEDB();
        BARRIER(); SCHEDB();

        int cur = 0, dst = 2;
        for (int t = 0; t < 32; ++t) {
            if (t + 2 < 32)
                GLD16(xtile + (size_t)(t + 2) * 8192 + tid * 16,
                      As + dst * 8192 + tid * 16);

            short8v afr[2];
            #pragma unroll
            for (int m = 0; m < 2; ++m) {
                int row = wr * 32 + m * 16 + l15;
                afr[m] = *(short8v*)(As + cur * 8192 + row * 64 +
                                     ((l4 ^ ((row >> 1) & 3)) * 16));
            }
            short8v bg8 = *(short8v*)(Bg + t * 2048 + boff);
            short8v bu8 = *(short8v*)(Bu + t * 2048 + boff);
            __builtin_amdgcn_s_setprio(1);
            accg[0] = __builtin_amdgcn_mfma_f32_16x16x32_bf16(afr[0], bg8, accg[0], 0, 0, 0);
            accg[1] = __builtin_amdgcn_mfma_f32_16x16x32_bf16(afr[1], bg8, accg[1], 0, 0, 0);
            accu[0] = __builtin_amdgcn_mfma_f32_16x16x32_bf16(afr[0], bu8, accu[0], 0, 0, 0);
            accu[1] = __builtin_amdgcn_mfma_f32_16x16x32_bf16(afr[1], bu8, accu[1], 0, 0, 0);
            __builtin_amdgcn_s_setprio(0);

            if (t + 2 < 32)      { WAIT_VM1(); }
            else if (t + 1 < 32) { WAIT_VM0(); }
            SCHEDB();
            if (t + 1 < 32) { BARRIER(); SCHEDB(); }
            cur = (cur == 2) ? 0 : cur + 1;
            dst = (dst == 2) ? 0 : dst + 1;
        }

        // epilogue: bias + clamp + GLU -> act granule tile (tt == p)
        char* atile = act + ((size_t)(e * 8 + rt)) * 262144;
        #pragma unroll
        for (int m = 0; m < 2; ++m) {
            int rbase = wr * 32 + m * 16 + l4 * 4;
            #pragma unroll
            for (int reg = 0; reg < 4; ++reg) {
                int r = rbase + reg;
                if (r >= rows_here) continue;
                float g = accg[m][reg] + bgb;
                float u = accu[m][reg] + bub;
                g = fminf(g, 7.0f);
                u = fminf(fmaxf(u, -7.0f), 7.0f);
                float glu = g / (1.0f + __expf(-1.702f * g));
                float a = (u + 1.0f) * glu;
                *(ushort*)(atile + (size_t)p * 8192 + r * 64 +
                           ((kq2 ^ ((r >> 1) & 3)) * 16) + ke * 2) = (ushort)bf16r(a);
            }
        }
    }
}

// ---------------- down MFMA GEMM (R6 form: 2-phase, 32 KB LDS) -> eout ----------------
__global__ __launch_bounds__(256, 4) void down_mfma(
    const char* __restrict__ act, const char* __restrict__ wbuf,
    const float* __restrict__ db, const int* __restrict__ counts,
    ushort* __restrict__ eout)
{
    const int lin = blockIdx.x;
    const int xcd = lin & 7, slot = lin >> 3;
    const int gg = (slot >> 3) * 8 + xcd;   // 0..255
    const int rt = slot & 7;
    const int e = gg >> 3, ct = gg & 7;

    const int n = counts[e];
    const int row0 = rt * 128;
    if (row0 >= n) return;
    const int rows_here = min(128, n - row0);
    const int c0 = ct * 128;

    __shared__ char AsB[2][8192];
    __shared__ char BsB[2][8192];

    const int tid = threadIdx.x;
    const int lane = tid & 63, wid = tid >> 6;
    const int wr = wid >> 1, wc = wid & 1;
    const int l15 = lane & 15, l4 = lane >> 4;

    const char* atile = act + ((size_t)(e * 8 + rt)) * 262144;
    const char* btile = wbuf + ((size_t)(e * 8 + ct) * 32) * 8192;

    f32x4 acc[4][4];
    #pragma unroll
    for (int m = 0; m < 4; m++)
        #pragma unroll
        for (int j = 0; j < 4; j++) acc[m][j] = (f32x4)0.f;

    auto stage = [&](int buf, int t) {
        const char* sa = atile + (size_t)t * 8192 + tid * 16;
        GLD16(sa, AsB[buf] + tid * 16);
        GLD16(sa + 4096, AsB[buf] + 4096 + tid * 16);
        const char* sb = btile + (size_t)t * 8192 + tid * 16;
        GLD16(sb, BsB[buf] + tid * 16);
        GLD16(sb + 4096, BsB[buf] + 4096 + tid * 16);
    };

    stage(0, 0);
    __syncthreads();
    int cur = 0;
    for (int t = 0; t < 32; ++t) {
        if (t < 31) stage(cur ^ 1, t + 1);

        short8v afr[4];
        #pragma unroll
        for (int m = 0; m < 4; ++m) {
            int row = wr * 64 + m * 16 + l15;
            afr[m] = *(short8v*)(AsB[cur] + row * 64 + ((l4 ^ ((row >> 1) & 3)) * 16));
        }
        __builtin_amdgcn_s_setprio(1);
        #pragma unroll
        for (int j = 0; j < 4; ++j) {
            int nn = wc * 64 + j * 16 + l15;
            short8v b8 = *(short8v*)(BsB[cur] + l4 * 2048 + nn * 16);
            #pragma unroll
            for (int m = 0; m < 4; ++m)
                acc[m][j] = __builtin_amdgcn_mfma_f32_16x16x32_bf16(afr[m], b8, acc[m][j], 0, 0, 0);
        }
        __builtin_amdgcn_s_setprio(0);
        __syncthreads();
        cur ^= 1;
    }

    #pragma unroll
    for (int j = 0; j < 4; ++j) {
        int col = c0 + wc * 64 + j * 16 + l15;
        float bias = db[(size_t)e * H_DIM + col];
        #pragma unroll
        for (int m = 0; m < 4; ++m) {
            int rbase = wr * 64 + m * 16 + l4 * 4;
            #pragma unroll
            for (int reg = 0; reg < 4; ++reg) {
                int r = rbase + reg;
                if (r >= rows_here) continue;
                eout[((size_t)e * CAP + row0 + r) * H_DIM + col] =
                    (ushort)bf16r(acc[m][j][reg] + bias);
            }
        }
    }
}

// ---------------- finalize: out[t] = sum_k w_k * eout[e_k, slot_k] ----------------
__global__ __launch_bounds__(256) void finalize_kernel(
    const ushort* __restrict__ eout, const int* __restrict__ flat_e,
    const float* __restrict__ flat_w, const int* __restrict__ pair_slot,
    float* __restrict__ out)
{
    const int t = blockIdx.x;
    const int c = threadIdx.x * 4;
    float a0 = 0.f, a1 = 0.f, a2 = 0.f, a3 = 0.f;
    #pragma unroll
    for (int k = 0; k < TOPK; ++k) {
        int p = t * TOPK + k;
        int s = pair_slot[p];
        if (s < 0) continue;
        int e = flat_e[p];
        float w = flat_w[p];
        const ushort* row = eout + ((size_t)e * CAP + s) * H_DIM + c;
        ushort4 v = *(const ushort4*)row;
        a0 += w * bf16_bits_to_f32(v.x);
        a1 += w * bf16_bits_to_f32(v.y);
        a2 += w * bf16_bits_to_f32(v.z);
        a3 += w * bf16_bits_to_f32(v.w);
    }
    *(float4*)(out + (size_t)t * H_DIM + c) = make_float4(a0, a1, a2, a3);
}

extern "C" void kernel_launch(void* const* d_in, const int* in_sizes, int n_in,
                              void* d_out, int out_size, void* d_ws, size_t ws_size,
                              hipStream_t stream) {
    const float* x   = (const float*)d_in[0];
    const float* rw  = (const float*)d_in[1];
    const float* rb  = (const float*)d_in[2];
    const float* wgu = (const float*)d_in[3];
    const float* gub = (const float*)d_in[4];
    const float* wd  = (const float*)d_in[5];
    const float* db  = (const float*)d_in[6];

    float* out    = (float*)d_out;
    float* scores = out + (size_t)T_TOK * H_DIM;

    char* ws = (char*)d_ws;
    char* xbuf = ws;                       // 64 MB granule-packed bf16 (overlay eout)
    ushort* eout = (ushort*)ws;
    size_t off = (size_t)E_EXP * CAP * H_DIM * 2;
    char* act     = ws + off;  off += (size_t)E_EXP * CAP * H_DIM * 2;  // 64 MB
    char* wbuf_dn = ws + off;  off += (size_t)E_EXP * 8 * 32 * 8192;    // 64 MB
    int*   flat_e     = (int*)(ws + off);   off += PAIRS * 4;
    float* flat_w     = (float*)(ws + off); off += PAIRS * 4;
    int*   slot_token = (int*)(ws + off);   off += E_EXP * CAP * 4;
    float* slot_w     = (float*)(ws + off); off += E_EXP * CAP * 4;
    int*   pair_slot  = (int*)(ws + off);   off += PAIRS * 4;
    int*   counts     = (int*)(ws + off);   off += E_EXP * 4;
    (void)ws_size; (void)out_size; (void)n_in; (void)in_sizes; (void)slot_w;

    // allow 152 KB dynamic LDS for the B-stationary gateup
    hipFuncSetAttribute((const void*)gateup_mfma,
                        hipFuncAttributeMaxDynamicSharedMemorySize, 155648);

    hipLaunchKernelGGL(router_kernel, dim3(T_TOK / 8), dim3(256), 0, stream,
                       x, rw, rb, scores, flat_e, flat_w);
    hipLaunchKernelGGL(scan_kernel, dim3(1), dim3(256), 0, stream,
                       flat_e, flat_w, slot_token, slot_w, pair_slot, counts);
    hipLaunchKernelGGL(stage_tokens, dim3(8, E_EXP), dim3(256), 0, stream,
                       x, slot_token, counts, xbuf);
    hipLaunchKernelGGL(conv_dn, dim3(8, 8, E_EXP), dim3(256), 0, stream, wd, wbuf_dn);
    hipLaunchKernelGGL(gateup_mfma, dim3(1024), dim3(512), 155648, stream,
                       xbuf, wgu, gub, counts, act);
    hipLaunchKernelGGL(down_mfma, dim3(2048), dim3(256), 0, stream,
                       act, wbuf_dn, db, counts, eout);
    hipLaunchKernelGGL(finalize_kernel, dim3(T_TOK), dim3(256), 0, stream,
                       eout, flat_e, flat_w, pair_slot, out);
}

// Round 11
// 471.341 us; speedup vs baseline: 1.1516x; 1.0766x over previous
//
#include <hip/hip_runtime.h>
#include <hip/hip_bf16.h>

#define T_TOK 4096
#define H_DIM 1024
#define E_EXP 32
#define TOPK 4
#define CAP 1024
#define PAIRS (T_TOK*TOPK)

typedef __attribute__((ext_vector_type(8))) short short8v;
typedef __attribute__((ext_vector_type(4))) float f32x4;
typedef unsigned long long u64;
typedef unsigned short ushort;

__device__ __forceinline__ float bf16_bits_to_f32(ushort h) {
    return __uint_as_float(((unsigned)h) << 16);
}
__device__ __forceinline__ unsigned bf16r(float f) {
    unsigned u = __float_as_uint(f);
    return ((u + 0x7fffu + ((u >> 16) & 1u)) >> 16) & 0xffffu;
}
__device__ __forceinline__ unsigned cvt2(float a, float b) {
    unsigned r;
    asm("v_cvt_pk_bf16_f32 %0, %1, %2" : "=v"(r) : "v"(a), "v"(b));
    return r;
}
__device__ __forceinline__ u64 pk4(float a, float b, float c, float d) {
    return (u64)cvt2(a, b) | ((u64)cvt2(c, d) << 32);
}

#define GLD16(gsrc, ldst) \
    __builtin_amdgcn_global_load_lds( \
        (const __attribute__((address_space(1))) unsigned*)(gsrc), \
        (__attribute__((address_space(3))) unsigned*)(ldst), 16, 0, 0)

#define WAIT_VM(N)   asm volatile("s_waitcnt vmcnt(" #N ")" ::: "memory")
#define WAIT_VMLG(N) asm volatile("s_waitcnt vmcnt(" #N ") lgkmcnt(0)" ::: "memory")
#define SCHEDB()     __builtin_amdgcn_sched_barrier(0)
#define BARRIER()    __builtin_amdgcn_s_barrier()

// ---------------- zero out-region ----------------
__global__ void zero_kernel(float4* __restrict__ p, int n4) {
    int i = blockIdx.x * blockDim.x + threadIdx.x;
    if (i < n4) p[i] = make_float4(0.f, 0.f, 0.f, 0.f);
}

// ---------------- router: 8 tokens/block, single rw pass ----------------
__global__ __launch_bounds__(256) void router_kernel(
    const float* __restrict__ x, const float* __restrict__ rw,
    const float* __restrict__ rb, float* __restrict__ scores,
    int* __restrict__ flat_e, float* __restrict__ flat_w)
{
    __shared__ float xs[8][H_DIM];   // 32 KB
    __shared__ float lg[8][E_EXP];
    const int t0 = blockIdx.x * 8;
    const int tid = threadIdx.x;

    for (int i = tid; i < 2048; i += 256) {   // 8 rows x 256 float4
        int row = i >> 8, c4 = i & 255;
        *(float4*)&xs[row][c4 * 4] =
            *(const float4*)(x + (size_t)(t0 + row) * H_DIM + c4 * 4);
    }
    __syncthreads();

    const int e = tid >> 3, l8 = tid & 7;
    float part[8];
    #pragma unroll
    for (int tt = 0; tt < 8; ++tt) part[tt] = 0.f;
    const float* wrow = rw + (size_t)e * H_DIM;
    for (int h = l8; h < H_DIM; h += 8) {
        float w = wrow[h];
        #pragma unroll
        for (int tt = 0; tt < 8; ++tt) part[tt] = fmaf(xs[tt][h], w, part[tt]);
    }
    #pragma unroll
    for (int tt = 0; tt < 8; ++tt) {
        float v = part[tt];
        v += __shfl_xor(v, 1);
        v += __shfl_xor(v, 2);
        v += __shfl_xor(v, 4);
        if (l8 == 0) lg[tt][e] = v + rb[e];
    }
    __syncthreads();

    if (tid < 8) {
        const int tt = tid, t = t0 + tt;
        unsigned used = 0;
        float bv[TOPK]; int bi[TOPK];
        #pragma unroll
        for (int j = 0; j < TOPK; j++) {
            float best = -1e30f; int bid = -1;
            for (int q = 0; q < E_EXP; q++) {
                if (used & (1u << q)) continue;
                if (lg[tt][q] > best) { best = lg[tt][q]; bid = q; }
            }
            used |= 1u << bid;
            bv[j] = best; bi[j] = bid;
        }
        const float m = bv[0];
        float s = 0.f; float w[TOPK];
        #pragma unroll
        for (int j = 0; j < TOPK; j++) { w[j] = expf(bv[j] - m); s += w[j]; }
        const float inv = 1.f / s;
        #pragma unroll
        for (int j = 0; j < TOPK; j++) w[j] *= inv;
        for (int q = 0; q < E_EXP; ++q) {
            float v = 0.f;
            #pragma unroll
            for (int j = 0; j < TOPK; j++) if (bi[j] == q) v = w[j];
            scores[(size_t)t * E_EXP + q] = v;
        }
        #pragma unroll
        for (int j = 0; j < TOPK; j++) {
            flat_e[t * TOPK + j] = bi[j];
            flat_w[t * TOPK + j] = w[j];
        }
    }
}

// ---------------- deterministic rank scan ----------------
__global__ __launch_bounds__(256) void scan_kernel(
    const int* __restrict__ flat_e, const float* __restrict__ flat_w,
    int* __restrict__ slot_token, float* __restrict__ slot_w,
    int* __restrict__ counts)
{
    __shared__ int cnt[256 * E_EXP];
    const int tid = threadIdx.x;
    for (int e = 0; e < E_EXP; e++) cnt[tid * E_EXP + e] = 0;
    __syncthreads();
    const int base = tid * (PAIRS / 256);
    for (int i = 0; i < PAIRS / 256; i++) {
        int e = flat_e[base + i];
        cnt[tid * E_EXP + e]++;
    }
    __syncthreads();
    if (tid < E_EXP) {
        int run = 0;
        for (int i = 0; i < 256; i++) {
            int idx = i * E_EXP + tid;
            int v = cnt[idx];
            cnt[idx] = run;
            run += v;
        }
        counts[tid] = min(run, CAP);
    }
    __syncthreads();
    for (int i = 0; i < PAIRS / 256; i++) {
        int p = base + i;
        int e = flat_e[p];
        int r = cnt[tid * E_EXP + e]++;
        if (r < CAP) {
            slot_token[e * CAP + r] = p >> 2;
            slot_w[e * CAP + r] = flat_w[p];
        }
    }
}

// ---------------- stage tokens: gather x -> granule-packed bf16 xbuf ----------------
__global__ __launch_bounds__(256) void stage_tokens(
    const float* __restrict__ x, const int* __restrict__ slot_token,
    const int* __restrict__ counts, char* __restrict__ xbuf)
{
    const int e = blockIdx.y, rt = blockIdx.x;
    const int n = counts[e];
    const int row0 = rt * 128;
    if (row0 >= n) return;
    const int rows_here = min(128, n - row0);
    const int lane = threadIdx.x & 63, wv = threadIdx.x >> 6;
    char* tb = xbuf + ((size_t)(e * 8 + rt)) * 262144;

    for (int r = wv; r < rows_here; r += 4) {
        const float* xr = x + (size_t)slot_token[e * CAP + row0 + r] * H_DIM;
        const int s = (r >> 1) & 3;
        #pragma unroll
        for (int half = 0; half < 2; ++half) {
            int gi = half * 64 + lane;
            float4 a = *(const float4*)(xr + gi * 8);
            float4 b = *(const float4*)(xr + gi * 8 + 4);
            uint4 w;
            w.x = cvt2(a.x, a.y); w.y = cvt2(a.z, a.w);
            w.z = cvt2(b.x, b.y); w.w = cvt2(b.z, b.w);
            int t = gi >> 2, kq = gi & 3;
            *(uint4*)(tb + (size_t)t * 8192 + r * 64 + ((kq ^ s) * 16)) = w;
        }
    }
}

// ---------------- gate_up MFMA GEMM (pipelined, counted vmcnt) ----------------
__global__ __launch_bounds__(256, 3) void gateup_mfma(
    const char* __restrict__ xbuf, const float* __restrict__ wgu,
    const float* __restrict__ gub, const int* __restrict__ counts,
    char* __restrict__ act)
{
    const int lin = blockIdx.x;
    const int xcd = lin & 7, slot = lin >> 3;
    const int gg = (slot >> 3) * 8 + xcd;
    const int rt = slot & 7;
    const int e = gg >> 4, ct = gg & 15;

    const int n = counts[e];
    const int row0 = rt * 128;
    if (row0 >= n) return;
    const int rows_here = min(128, n - row0);
    const int c0f = ct * 64, c0gu = ct * 128;

    __shared__ char AsB[2][8192];
    __shared__ char BgB[2][4096];
    __shared__ char BuB[2][4096];

    const int tid = threadIdx.x;
    const int lane = tid & 63, wid = tid >> 6;
    const int wr = wid >> 1, wc = wid & 1;
    const int l15 = lane & 15, l4 = lane >> 4;
    const int bnp = tid & 63, bkq0 = tid >> 6;

    const char* xtile = xbuf + ((size_t)(e * 8 + rt)) * 262144;

    f32x4 accg[4][2], accu[4][2];
    #pragma unroll
    for (int m = 0; m < 4; m++)
        #pragma unroll
        for (int j = 0; j < 2; j++) { accg[m][j] = (f32x4)0.f; accu[m][j] = (f32x4)0.f; }

    float2 bv0[8], bv1[8];
    int cur = 0;

    auto stageA = [&](int buf, int t) {
        const char* sa = xtile + (size_t)t * 8192 + tid * 16;
        GLD16(sa, AsB[buf] + tid * 16);
        GLD16(sa + 4096, AsB[buf] + 4096 + tid * 16);
    };
    auto bload = [&](float2 (&ld)[8], int t) {
        #pragma unroll
        for (int u = 0; u < 2; ++u) {
            const float* src = wgu + ((size_t)e * 1024 + t * 32 + (bkq0 + 4 * u) * 4) * 2048
                               + c0gu + 2 * bnp;
            #pragma unroll
            for (int q = 0; q < 4; ++q) ld[u * 4 + q] = *(const float2*)(src + (size_t)q * 2048);
        }
    };
    auto bpack = [&](int buf, float2 (&pk)[8]) {
        #pragma unroll
        for (int u = 0; u < 2; ++u) {
            int kq = bkq0 + 4 * u;
            char* dg = BgB[buf] + (kq >> 1) * 1024 + bnp * 16 + (kq & 1) * 8;
            char* du = BuB[buf] + (kq >> 1) * 1024 + bnp * 16 + (kq & 1) * 8;
            *(u64*)dg = pk4(pk[u*4+0].x, pk[u*4+1].x, pk[u*4+2].x, pk[u*4+3].x);
            *(u64*)du = pk4(pk[u*4+0].y, pk[u*4+1].y, pk[u*4+2].y, pk[u*4+3].y);
        }
    };
    auto compute = [&]() {
        short8v afr[4];
        #pragma unroll
        for (int m = 0; m < 4; ++m) {
            int row = wr * 64 + m * 16 + l15;
            afr[m] = *(short8v*)(AsB[cur] + row * 64 + ((l4 ^ ((row >> 1) & 3)) * 16));
        }
        __builtin_amdgcn_s_setprio(1);
        #pragma unroll
        for (int j = 0; j < 2; ++j) {
            int fl = wc * 32 + j * 16 + l15;
            short8v bg8 = *(short8v*)(BgB[cur] + l4 * 1024 + fl * 16);
            short8v bu8 = *(short8v*)(BuB[cur] + l4 * 1024 + fl * 16);
            #pragma unroll
            for (int m = 0; m < 4; ++m) {
                accg[m][j] = __builtin_amdgcn_mfma_f32_16x16x32_bf16(afr[m], bg8, accg[m][j], 0, 0, 0);
                accu[m][j] = __builtin_amdgcn_mfma_f32_16x16x32_bf16(afr[m], bu8, accu[m][j], 0, 0, 0);
            }
        }
        __builtin_amdgcn_s_setprio(0);
    };

    // prologue: A(0) [2 vm], B(0)->bv0 [8], B(1)->bv1 [8]
    stageA(0, 0);
    bload(bv0, 0);
    bload(bv1, 1);
    WAIT_VM(8); SCHEDB();
    bpack(0, bv0);
    WAIT_VMLG(8); SCHEDB();
    BARRIER(); SCHEDB();

    #define GU_ITER(T, LD, PK) { \
        stageA(cur ^ 1, (T) + 1); \
        bload(LD, (T) + 2); \
        compute(); SCHEDB(); \
        WAIT_VM(10); SCHEDB(); \
        bpack(cur ^ 1, PK); \
        WAIT_VMLG(8); SCHEDB(); \
        BARRIER(); SCHEDB(); \
        cur ^= 1; }

    for (int t = 0; t < 30; t += 2) {
        GU_ITER(t, bv0, bv1);
        GU_ITER(t + 1, bv1, bv0);
    }
    #undef GU_ITER
    stageA(cur ^ 1, 31);
    compute(); SCHEDB();
    WAIT_VM(2); SCHEDB();
    bpack(cur ^ 1, bv1);
    WAIT_VMLG(0); SCHEDB();
    BARRIER(); SCHEDB();
    cur ^= 1;
    compute();

    // epilogue: bias + clamp + GLU -> act (granule-packed, k-dim = f)
    char* atile = act + ((size_t)(e * 8 + rt)) * 262144;
    #pragma unroll
    for (int j = 0; j < 2; ++j) {
        int f = c0f + wc * 32 + j * 16 + l15;
        float bgb = gub[(size_t)e * 2048 + 2 * f];
        float bub = gub[(size_t)e * 2048 + 2 * f + 1];
        int tt = f >> 5, kq = (f & 31) >> 3, ke = f & 7;
        #pragma unroll
        for (int m = 0; m < 4; ++m) {
            int rbase = wr * 64 + m * 16 + l4 * 4;
            #pragma unroll
            for (int reg = 0; reg < 4; ++reg) {
                int r = rbase + reg;
                if (r >= rows_here) continue;
                float g = accg[m][j][reg] + bgb;
                float u = accu[m][j][reg] + bub;
                g = fminf(g, 7.0f);
                u = fminf(fmaxf(u, -7.0f), 7.0f);
                float glu = g / (1.0f + __expf(-1.702f * g));
                float a = (u + 1.0f) * glu;
                *(ushort*)(atile + (size_t)tt * 8192 + r * 64 +
                           ((kq ^ ((r >> 1) & 3)) * 16) + ke * 2) = (ushort)bf16r(a);
            }
        }
    }
}

// ---------------- down MFMA GEMM (pipelined) + fused weighted atomic scatter ----------------
__global__ __launch_bounds__(256, 3) void down_mfma(
    const char* __restrict__ act, const float* __restrict__ wd,
    const float* __restrict__ db, const int* __restrict__ counts,
    const int* __restrict__ slot_token, const float* __restrict__ slot_w,
    float* __restrict__ out)
{
    const int lin = blockIdx.x;
    const int xcd = lin & 7, slot = lin >> 3;
    const int gg = (slot >> 3) * 8 + xcd;
    const int rt = slot & 7;
    const int e = gg >> 3, ct = gg & 7;

    const int n = counts[e];
    const int row0 = rt * 128;
    if (row0 >= n) return;
    const int rows_here = min(128, n - row0);
    const int c0 = ct * 128;

    __shared__ char AsB[2][8192];
    __shared__ char BsB[2][8192];
    __shared__ int tok_s[128];
    __shared__ float wrow_s[128];

    const int tid = threadIdx.x;
    if (tid < 128) {
        if (tid < rows_here) {
            tok_s[tid] = slot_token[e * CAP + row0 + tid];
            wrow_s[tid] = slot_w[e * CAP + row0 + tid];
        } else { tok_s[tid] = 0; wrow_s[tid] = 0.f; }
    }
    __syncthreads();

    const int lane = tid & 63, wid = tid >> 6;
    const int wr = wid >> 1, wc = wid & 1;
    const int l15 = lane & 15, l4 = lane >> 4;
    const int bnp = tid & 63, bkq0 = tid >> 6;

    const char* atile = act + ((size_t)(e * 8 + rt)) * 262144;

    f32x4 acc[4][4];
    #pragma unroll
    for (int m = 0; m < 4; m++)
        #pragma unroll
        for (int j = 0; j < 4; j++) acc[m][j] = (f32x4)0.f;

    float2 bv0[8], bv1[8];
    int cur = 0;

    auto stageA = [&](int buf, int t) {
        const char* sa = atile + (size_t)t * 8192 + tid * 16;
        GLD16(sa, AsB[buf] + tid * 16);
        GLD16(sa + 4096, AsB[buf] + 4096 + tid * 16);
    };
    auto bload = [&](float2 (&ld)[8], int t) {
        #pragma unroll
        for (int u = 0; u < 2; ++u) {
            const float* src = wd + ((size_t)e * 1024 + t * 32 + (bkq0 + 4 * u) * 4) * 1024
                               + c0 + 2 * bnp;
            #pragma unroll
            for (int q = 0; q < 4; ++q) ld[u * 4 + q] = *(const float2*)(src + (size_t)q * 1024);
        }
    };
    auto bpack = [&](int buf, float2 (&pk)[8]) {
        #pragma unroll
        for (int u = 0; u < 2; ++u) {
            int kq = bkq0 + 4 * u;
            char* d0 = BsB[buf] + (kq >> 1) * 2048 + (2 * bnp) * 16 + (kq & 1) * 8;
            *(u64*)d0        = pk4(pk[u*4+0].x, pk[u*4+1].x, pk[u*4+2].x, pk[u*4+3].x);
            *(u64*)(d0 + 16) = pk4(pk[u*4+0].y, pk[u*4+1].y, pk[u*4+2].y, pk[u*4+3].y);
        }
    };
    auto compute = [&]() {
        short8v afr[4];
        #pragma unroll
        for (int m = 0; m < 4; ++m) {
            int row = wr * 64 + m * 16 + l15;
            afr[m] = *(short8v*)(AsB[cur] + row * 64 + ((l4 ^ ((row >> 1) & 3)) * 16));
        }
        __builtin_amdgcn_s_setprio(1);
        #pragma unroll
        for (int j = 0; j < 4; ++j) {
            int nn = wc * 64 + j * 16 + l15;
            short8v b8 = *(short8v*)(BsB[cur] + l4 * 2048 + nn * 16);
            #pragma unroll
            for (int m = 0; m < 4; ++m)
                acc[m][j] = __builtin_amdgcn_mfma_f32_16x16x32_bf16(afr[m], b8, acc[m][j], 0, 0, 0);
        }
        __builtin_amdgcn_s_setprio(0);
    };

    stageA(0, 0);
    bload(bv0, 0);
    bload(bv1, 1);
    WAIT_VM(8); SCHEDB();
    bpack(0, bv0);
    WAIT_VMLG(8); SCHEDB();
    BARRIER(); SCHEDB();

    #define DN_ITER(T, LD, PK) { \
        stageA(cur ^ 1, (T) + 1); \
        bload(LD, (T) + 2); \
        compute(); SCHEDB(); \
        WAIT_VM(10); SCHEDB(); \
        bpack(cur ^ 1, PK); \
        WAIT_VMLG(8); SCHEDB(); \
        BARRIER(); SCHEDB(); \
        cur ^= 1; }

    for (int t = 0; t < 30; t += 2) {
        DN_ITER(t, bv0, bv1);
        DN_ITER(t + 1, bv1, bv0);
    }
    #undef DN_ITER
    stageA(cur ^ 1, 31);
    compute(); SCHEDB();
    WAIT_VM(2); SCHEDB();
    bpack(cur ^ 1, bv1);
    WAIT_VMLG(0); SCHEDB();
    BARRIER(); SCHEDB();
    cur ^= 1;
    compute();

    // epilogue: bias + weighted atomic scatter directly to out
    #pragma unroll
    for (int j = 0; j < 4; ++j) {
        int col = c0 + wc * 64 + j * 16 + l15;
        float bias = db[(size_t)e * H_DIM + col];
        #pragma unroll
        for (int m = 0; m < 4; ++m) {
            int rbase = wr * 64 + m * 16 + l4 * 4;
            #pragma unroll
            for (int reg = 0; reg < 4; ++reg) {
                int r = rbase + reg;
                if (r >= rows_here) continue;
                atomicAdd(out + (size_t)tok_s[r] * H_DIM + col,
                          wrow_s[r] * (acc[m][j][reg] + bias));
            }
        }
    }
}

extern "C" void kernel_launch(void* const* d_in, const int* in_sizes, int n_in,
                              void* d_out, int out_size, void* d_ws, size_t ws_size,
                              hipStream_t stream) {
    const float* x   = (const float*)d_in[0];
    const float* rw  = (const float*)d_in[1];
    const float* rb  = (const float*)d_in[2];
    const float* wgu = (const float*)d_in[3];
    const float* gub = (const float*)d_in[4];
    const float* wd  = (const float*)d_in[5];
    const float* db  = (const float*)d_in[6];

    float* out    = (float*)d_out;
    float* scores = out + (size_t)T_TOK * H_DIM;

    char* ws = (char*)d_ws;
    char* xbuf = ws;                       // 64 MB granule-packed bf16
    size_t off = (size_t)E_EXP * CAP * H_DIM * 2;
    char* act  = ws + off;  off += (size_t)E_EXP * CAP * H_DIM * 2;   // 64 MB
    int*   flat_e     = (int*)(ws + off);   off += PAIRS * 4;
    float* flat_w     = (float*)(ws + off); off += PAIRS * 4;
    int*   slot_token = (int*)(ws + off);   off += E_EXP * CAP * 4;
    float* slot_w     = (float*)(ws + off); off += E_EXP * CAP * 4;
    int*   counts     = (int*)(ws + off);   off += E_EXP * 4;
    (void)ws_size; (void)out_size; (void)n_in; (void)in_sizes;

    hipLaunchKernelGGL(zero_kernel, dim3(4096), dim3(256), 0, stream,
                       (float4*)out, (T_TOK * H_DIM) / 4);
    hipLaunchKernelGGL(router_kernel, dim3(T_TOK / 8), dim3(256), 0, stream,
                       x, rw, rb, scores, flat_e, flat_w);
    hipLaunchKernelGGL(scan_kernel, dim3(1), dim3(256), 0, stream,
                       flat_e, flat_w, slot_token, slot_w, counts);
    hipLaunchKernelGGL(stage_tokens, dim3(8, E_EXP), dim3(256), 0, stream,
                       x, slot_token, counts, xbuf);
    hipLaunchKernelGGL(gateup_mfma, dim3(4096), dim3(256), 0, stream,
                       xbuf, wgu, gub, counts, act);
    hipLaunchKernelGGL(down_mfma, dim3(2048), dim3(256), 0, stream,
                       act, wd, db, counts, slot_token, slot_w, out);
}